// Round 7
// baseline (126.469 us; speedup 1.0000x reference)
//
#include <hip/hip_runtime.h>
#include <math.h>

// CRF loss: B=256, L=256, T=50. ONE WAVE per batch element, barrier-free scan.
// lane = "to" tag (>=50 pad, v=0).
//
// R7: exp-domain recurrence via MFMA.
//   alpha_{l}[to] = (sum_f alpha_{l-1}[f] * E2[f][to]) * ehat_l[to],
//   E2[f][to] = exp2(trans[f][to]/ln2) (constant bf16 B-frags),
//   ehat = exp2(emit/ln2) (prefetched, off critical path).
// State: alpha = v * 2^S. Renorm each step: rr = rcp(v[0]), v *= rr, S += log2(v0)
// (log2 off critical path). No per-step exp2/log2 round trip, no readlane dot.
// Matvec = 8 x mfma_f32_16x16x32_bf16: 4 to-tiles (N=16) x 2 K-chunks (K=32).
// Layouts (HW-verified): A[m=lane&15][k=(lane>>4)*8+j], B[k=(lane>>4)*8+j][n=lane&15],
// D col=lane&15 -> lane `to` selects its own result with 3 cndmasks.

#define TAGS 50
#define LEN 256
#define INV_LN2 1.4426950408889634f
#define LN2 0.6931471805599453f

typedef __attribute__((ext_vector_type(8))) short bf16x8;
typedef __attribute__((ext_vector_type(4))) float f32x4;

#if __has_builtin(__builtin_amdgcn_exp2f)
#define EXP2F(x) __builtin_amdgcn_exp2f(x)
#else
#define EXP2F(x) exp2f(x)
#endif
#if __has_builtin(__builtin_amdgcn_logf)
#define LOG2F(x) __builtin_amdgcn_logf(x)
#else
#define LOG2F(x) log2f(x)
#endif
#if __has_builtin(__builtin_amdgcn_rcpf)
#define RCPF(x) __builtin_amdgcn_rcpf(x)
#else
#define RCPF(x) (1.0f / (x))
#endif

__device__ __forceinline__ float readlane_f(float v, int srclane) {
  return __builtin_bit_cast(float,
      __builtin_amdgcn_readlane(__builtin_bit_cast(int, v), srclane));
}

// Pack two fp32 into one VGPR as (bf16(hi) << 16) | bf16(lo), round-half-up.
__device__ __forceinline__ int bf16pair(float lo, float hi) {
  unsigned lb = (__builtin_bit_cast(unsigned, lo) + 0x8000u) >> 16;
  unsigned hb = (__builtin_bit_cast(unsigned, hi) + 0x8000u) & 0xFFFF0000u;
  return (int)(hb | lb);
}

__global__ __launch_bounds__(64) void crf_fwd_kernel(
    const float* __restrict__ feats,   // (B, L, T)
    const float* __restrict__ trans,   // (T, T)
    const int*   __restrict__ tags,    // (B, L)
    const int*   __restrict__ mask,    // (B, L)
    float*       __restrict__ out)     // (B,)
{
  const int b    = blockIdx.x;
  const int lane = threadIdx.x;                       // "to" tag (>=50 pad)
  const int toc  = lane < TAGS ? lane : (TAGS - 1);
  const int q    = lane >> 4;                         // MFMA quad group
  const int n    = lane & 15;                         // MFMA col within tile

  __shared__ __align__(16) float feats_lds[LEN * TAGS]; // emits, prescaled by 1/ln2
  __shared__ int mask_lds[LEN];

  const float* fb = feats + (size_t)b * (LEN * TAGS);
  const int*   tb = tags + b * LEN;
  const int*   mb = mask + b * LEN;

  // Tags for gold score into registers (latency overlaps preload).
  int tg_c[4], tg_p[4];
#pragma unroll
  for (int k = 0; k < 4; ++k) {
    const int p = lane + 64 * k;
    tg_c[k] = tb[p];
    tg_p[k] = (p >= 1) ? tb[p - 1] : 0;
  }

  // ---- Bulk preload: feats[b] (prescaled) + mask[b] ----
  {
    const float4* fv = (const float4*)fb;             // 3200 float4
    for (int i = lane; i < (LEN * TAGS) / 4; i += 64) {
      float4 v = fv[i];
      v.x *= INV_LN2; v.y *= INV_LN2; v.z *= INV_LN2; v.w *= INV_LN2;
      *(float4*)&feats_lds[i * 4] = v;
    }
    for (int i = lane; i < LEN; i += 64) mask_lds[i] = mb[i];
  }

  // ---- Constant B-frags: E2[f][to] = exp2(trans[f][to]/ln2), bf16, pads = 0 ----
  union U8 { int i[4]; bf16x8 v; };
  U8 Bfr[4][2];                                       // [to-tile][k-chunk]
#pragma unroll
  for (int t = 0; t < 4; ++t)
#pragma unroll
    for (int c = 0; c < 2; ++c)
#pragma unroll
      for (int r = 0; r < 4; ++r) {
        const int f0 = 32 * c + 8 * q + 2 * r;
        const int to = 16 * t + n;
        const float e0 = (f0 < TAGS && to < TAGS)
            ? EXP2F(trans[f0 * TAGS + to] * INV_LN2) : 0.0f;
        const float e1 = (f0 + 1 < TAGS && to < TAGS)
            ? EXP2F(trans[(f0 + 1) * TAGS + to] * INV_LN2) : 0.0f;
        Bfr[t][c].i[r] = bf16pair(e0, e1);
      }

  // bpermute byte addresses for A-frag gather: src lane = 32c + 8q + 2r.
  int addrA[2][4];
#pragma unroll
  for (int c = 0; c < 2; ++c)
#pragma unroll
    for (int r = 0; r < 4; ++r)
      addrA[c][r] = (32 * c + 8 * q + 2 * r) * 4;

  __syncthreads();                                    // single wave: just a waitcnt

  // Init: alpha_0 = exp2(e0); v = exp2(e0 - c0), S = c0, pads v = 0.
  const float padf = (lane < TAGS) ? 1.0f : 0.0f;
  const float e0 = feats_lds[toc];
  const float c0 = readlane_f(e0, 0);
  float v = EXP2F(e0 - c0) * padf;
  float S = c0;

  float ehat_nxt = EXP2F(feats_lds[TAGS + toc]) * padf;
  int   m_nxt = mask_lds[1];

  const f32x4 zero4 = {0.0f, 0.0f, 0.0f, 0.0f};

  for (int l = 1; l < LEN; ++l) {
    const float ehat = ehat_nxt;
    const int   m_cur = m_nxt;
    const int   ln = (l + 1 < LEN) ? (l + 1) : (LEN - 1);
    const float e_raw = feats_lds[ln * TAGS + toc];
    m_nxt = mask_lds[ln];

    // ---- Pack v pairs to bf16: lanes 2i,2i+1 both hold (v[2i], v[2i+1]) ----
    const float partner = __shfl_xor(v, 1, 64);
    const float lo = (lane & 1) ? partner : v;
    const float hi = (lane & 1) ? v : partner;
    const int pk = bf16pair(lo, hi);

    // ---- Gather A-frags (v broadcast over m): 8 bpermutes ----
    U8 A0, A1;
#pragma unroll
    for (int r = 0; r < 4; ++r) {
      A0.i[r] = __builtin_amdgcn_ds_bpermute(addrA[0][r], pk);
      A1.i[r] = __builtin_amdgcn_ds_bpermute(addrA[1][r], pk);
    }

    // ---- Matvec: 4 to-tiles x 2 k-chunks ----
    f32x4 d0 = __builtin_amdgcn_mfma_f32_16x16x32_bf16(A0.v, Bfr[0][0].v, zero4, 0, 0, 0);
    f32x4 d1 = __builtin_amdgcn_mfma_f32_16x16x32_bf16(A0.v, Bfr[1][0].v, zero4, 0, 0, 0);
    f32x4 d2 = __builtin_amdgcn_mfma_f32_16x16x32_bf16(A0.v, Bfr[2][0].v, zero4, 0, 0, 0);
    f32x4 d3 = __builtin_amdgcn_mfma_f32_16x16x32_bf16(A0.v, Bfr[3][0].v, zero4, 0, 0, 0);
    d0 = __builtin_amdgcn_mfma_f32_16x16x32_bf16(A1.v, Bfr[0][1].v, d0, 0, 0, 0);
    d1 = __builtin_amdgcn_mfma_f32_16x16x32_bf16(A1.v, Bfr[1][1].v, d1, 0, 0, 0);
    d2 = __builtin_amdgcn_mfma_f32_16x16x32_bf16(A1.v, Bfr[2][1].v, d2, 0, 0, 0);
    d3 = __builtin_amdgcn_mfma_f32_16x16x32_bf16(A1.v, Bfr[3][1].v, d3, 0, 0, 0);

    // ---- Select own column: to = 16*(lane>>4) + (lane&15) = lane ----
    const float p01 = (lane & 16) ? d1[0] : d0[0];
    const float p23 = (lane & 16) ? d3[0] : d2[0];
    const float d   = (lane & 32) ? p23 : p01;

    const float cand = d * ehat;                      // pads: 0 * 0 = 0
    const float vnew = (m_cur > 0) ? cand : v;        // masked: alpha unchanged
    const float cc = readlane_f(vnew, 0);             // renorm pivot (> 0)
    const float rr = RCPF(cc);
    v = vnew * rr;                                    // v[0] ~= 1
    S += LOG2F(cc);                                   // off critical path
    ehat_nxt = EXP2F(e_raw) * padf;                   // off critical path
  }

  // ---- Final: all_path = ln2 * (S + log2(sum v)) ----
  float sum = v;                                      // pads are 0
#pragma unroll
  for (int off = 32; off; off >>= 1) sum += __shfl_xor(sum, off, 64);

  // ---- Gold score: lane handles positions lane, lane+64, lane+128, lane+192 ----
  float gp = 0.0f;
#pragma unroll
  for (int k = 0; k < 4; ++k) {
    const int p = lane + 64 * k;
    if (mask_lds[p] > 0) {
      float vv = feats_lds[p * TAGS + tg_c[k]] * LN2; // un-prescale
      if (p >= 1) vv += trans[tg_p[k] * TAGS + tg_c[k]];
      gp += vv;
    }
  }
#pragma unroll
  for (int off = 32; off; off >>= 1) gp += __shfl_xor(gp, off, 64);

  if (lane == 0) {
    const float all_path = LN2 * (S + LOG2F(sum));
    out[b] = all_path - gp;
  }
}

extern "C" void kernel_launch(void* const* d_in, const int* in_sizes, int n_in,
                              void* d_out, int out_size, void* d_ws, size_t ws_size,
                              hipStream_t stream) {
  const float* feats = (const float*)d_in[0];
  const float* trans = (const float*)d_in[1];
  const int*   tags  = (const int*)d_in[2];
  const int*   mask  = (const int*)d_in[3];
  float* out = (float*)d_out;

  const int B = out_size;  // 256
  crf_fwd_kernel<<<B, 64, 0, stream>>>(feats, trans, tags, mask, out);
}